// Round 9
// baseline (178.427 us; speedup 1.0000x reference)
//
#include <hip/hip_runtime.h>

typedef _Float16 half_t;
typedef __attribute__((ext_vector_type(4))) _Float16 half4;
typedef __attribute__((ext_vector_type(8))) _Float16 half8;
typedef __attribute__((ext_vector_type(4))) float floatx4;

#define MFMA_F16(A,B,C)  __builtin_amdgcn_mfma_f32_16x16x32_f16(A,B,C,0,0,0)

typedef __attribute__((address_space(1))) const void gvoid_t;
typedef __attribute__((address_space(3))) void svoid_t;

// async global->LDS, 16B per lane, dest = wave-uniform base + lane*16
__device__ __forceinline__ void async_copy16(const half_t* g, half_t* l) {
    __builtin_amdgcn_global_load_lds((gvoid_t*)g, (svoid_t*)l, 16, 0, 0);
}

// ============================================================================
// Prep: x fp32 -> fp16 (xh); w_qkv, w_proj fp32 -> fp16 TRANSPOSED.
// blocks: [0,6144) x-convert; [6144,6576) w_qkv 64x64 tiles; [6576,6720) w_proj
// ============================================================================
__global__ __launch_bounds__(256)
void prep_kernel(const float* __restrict__ x, const float* __restrict__ w_qkv,
                 const float* __restrict__ w_proj, half_t* __restrict__ xh,
                 half_t* __restrict__ wqkvT, half_t* __restrict__ wprojT)
{
    __shared__ half_t tile[64 * 65];
    const int id = blockIdx.x, tid = threadIdx.x;
    if (id < 6144) {
        size_t e = (size_t)id * 1024 + tid * 4;
        float4 f = *(const float4*)(x + e);
        half4 h = { (half_t)f.x, (half_t)f.y, (half_t)f.z, (half_t)f.w };
        *(half4*)(xh + e) = h;
        return;
    }
    const float* src; half_t* dst; int lds, tr0, tc0;
    if (id < 6576) { int t = id - 6144; src = w_qkv; dst = wqkvT; lds = 2304;
                     tr0 = (t / 36) * 64; tc0 = (t % 36) * 64; }
    else           { int t = id - 6576; src = w_proj; dst = wprojT; lds = 768;
                     tr0 = (t / 12) * 64; tc0 = (t % 12) * 64; }
    #pragma unroll
    for (int i = 0; i < 4; i++) {
        int e = tid + i * 256, r = e >> 4, c4 = (e & 15) << 2;
        float4 f = *(const float4*)(src + (size_t)(tr0 + r) * lds + tc0 + c4);
        tile[(c4 + 0) * 65 + r] = (half_t)f.x;
        tile[(c4 + 1) * 65 + r] = (half_t)f.y;
        tile[(c4 + 2) * 65 + r] = (half_t)f.z;
        tile[(c4 + 3) * 65 + r] = (half_t)f.w;
    }
    __syncthreads();
    #pragma unroll
    for (int i = 0; i < 4; i++) {
        int e = tid + i * 256, c = e >> 4, r4 = (e & 15) << 2;
        half4 h = { tile[c * 65 + r4], tile[c * 65 + r4 + 1],
                    tile[c * 65 + r4 + 2], tile[c * 65 + r4 + 3] };
        *(half4*)(dst + (size_t)(tc0 + c) * 768 + tr0 + r4) = h;
    }
}

// ============================================================================
// QKV GEMM v9 (r8, PROVEN BEST): 256x288, BK=32, 8 waves, grid 256 = 1
// block/CU, 2 LDS buffers, ONE __syncthreads/step, REG-STAGING
// (global->VGPR->ds_write; off the rate-limited global_load_lds DMA path).
// ============================================================================
__global__ __launch_bounds__(512, 1)
void gemm_qkv(const half_t* __restrict__ A, const half_t* __restrict__ Bt,
              half_t* __restrict__ q_ws, half_t* __restrict__ k_ws,
              half_t* __restrict__ v_ws)
{
    __shared__ half_t As[2][256 * 32];   // 2 x 16 KB
    __shared__ half_t Bs[2][288 * 32];   // 2 x 18 KB  => 68 KB total

    const int lin  = blockIdx.x;                  // 0..255
    const int xcd  = lin & 7, rest = lin >> 3;    // rest 0..31
    const int m0 = ((rest >> 3) * 8 + xcd) * 256; // 32 m-strips; same-m -> XCD
    const int n0 = (rest & 7) * 288;              // 8 n-strips

    const int tid  = threadIdx.x;
    const int lane = tid & 63;
    const int w    = tid >> 6;                    // 0..7
    const int wm   = w >> 1, wn = w & 1;          // 4M x 2N wave grid
    const int quad = lane >> 4, l16 = lane & 15;

    // staging source mapping: lane -> (row_log, q_log)
    const int b0p = (lane ^ (lane >> 2) ^ (lane >> 4)) & 1;
    const int b1p = ((lane >> 1) ^ (lane >> 3)) & 1;
    const int b2p = ((lane >> 2) ^ (lane >> 4)) & 1;
    const int row_log = ((lane >> 2) & 0xC) | ((lane >> 2) & 2) | b2p; // 0..15
    const int q_log   = (b1p << 1) | b0p;                              // 0..3

    // read-side: logical (row=l16, kchunk=quad) -> phys offset in halfs
    const int foff = ((((l16 << 2) | quad) ^ (l16 & 7)) << 3);

    const half_t* aBase = A  + (size_t)(m0 + row_log) * 768 + q_log * 8;
    const half_t* bBase = Bt + (size_t)(n0 + row_log) * 768 + q_log * 8;

    floatx4 acc[4][9];
    #pragma unroll
    for (int i = 0; i < 4; i++)
        #pragma unroll
        for (int j = 0; j < 9; j++) acc[i][j] = (floatx4)0.0f;

    half8 sA0, sA1, sB0, sB1, sB2;

    #define LOADR(KO)                                                          \
        do {                                                                   \
            sA0 = *(const half8*)(aBase + (size_t)((w*2+0)*16) * 768 + (KO));  \
            sA1 = *(const half8*)(aBase + (size_t)((w*2+1)*16) * 768 + (KO));  \
            sB0 = *(const half8*)(bBase + (size_t)((w*2+0)*16) * 768 + (KO));  \
            sB1 = *(const half8*)(bBase + (size_t)((w*2+1)*16) * 768 + (KO));  \
            if (w < 2)                                                         \
                sB2 = *(const half8*)(bBase + (size_t)((16+w)*16) * 768 + (KO)); \
        } while (0)

    #define WRITES(BUF)                                                        \
        do {                                                                   \
            *(half8*)(&As[BUF][(w*2+0)*512 + lane*8]) = sA0;                   \
            *(half8*)(&As[BUF][(w*2+1)*512 + lane*8]) = sA1;                   \
            *(half8*)(&Bs[BUF][(w*2+0)*512 + lane*8]) = sB0;                   \
            *(half8*)(&Bs[BUF][(w*2+1)*512 + lane*8]) = sB1;                   \
            if (w < 2)                                                         \
                *(half8*)(&Bs[BUF][(16+w)*512 + lane*8]) = sB2;                \
        } while (0)

    LOADR(0);
    WRITES(0);
    __syncthreads();

    #pragma unroll 1
    for (int t = 0; t < 24; ++t) {
        const int cur = t & 1;
        if (t < 23) LOADR((t + 1) * 32);   // issue early; lands during compute

        half8 a[4], b[9];
        #pragma unroll
        for (int mi = 0; mi < 4; mi++)
            a[mi] = *(const half8*)(&As[cur][(wm*4 + mi) * 512 + foff]);
        #pragma unroll
        for (int ni = 0; ni < 9; ni++)
            b[ni] = *(const half8*)(&Bs[cur][(wn*9 + ni) * 512 + foff]);
        #pragma unroll
        for (int mi = 0; mi < 4; mi++)
            #pragma unroll
            for (int ni = 0; ni < 9; ni++)
                acc[mi][ni] = MFMA_F16(a[mi], b[ni], acc[mi][ni]);

        if (t < 23) WRITES(cur ^ 1);
        __syncthreads();
    }
    #undef LOADR
    #undef WRITES

    // epilogue (C layout: col = l16, row = quad*4 + reg)
    const int bb  = (m0 + wm * 64) >> 10;
    const int t0w = (m0 + wm * 64) & 1023;

    #pragma unroll
    for (int ni = 0; ni < 9; ni++) {
        const int cb  = n0 + wn * 144 + ni * 16;
        const int sel = (cb >= 1536) ? 2 : (cb >= 768 ? 1 : 0);
        const int rem = cb - sel * 768;
        const int hh  = rem >> 6;
        const int d   = (rem & 63) + l16;
        const size_t base = (size_t)(bb * 12 + hh) * 65536;

        if (sel == 0) {                     // q -> qT[d][tok], scaled, half4
            #pragma unroll
            for (int mi = 0; mi < 4; mi++) {
                int tok = t0w + mi * 16 + quad * 4;
                half4 hv = { (half_t)(acc[mi][ni][0] * 0.125f),
                             (half_t)(acc[mi][ni][1] * 0.125f),
                             (half_t)(acc[mi][ni][2] * 0.125f),
                             (half_t)(acc[mi][ni][3] * 0.125f) };
                *(half4*)(q_ws + base + (size_t)d * 1024 + tok) = hv;
            }
        } else if (sel == 1) {              // k -> [tok][d], scalar
            #pragma unroll
            for (int mi = 0; mi < 4; mi++)
                #pragma unroll
                for (int r = 0; r < 4; r++) {
                    int tok = t0w + mi * 16 + quad * 4 + r;
                    k_ws[base + (size_t)tok * 64 + d] = (half_t)acc[mi][ni][r];
                }
        } else {                            // v -> vT'[d][tokp], half4
            #pragma unroll
            for (int mi = 0; mi < 4; mi++) {
                int tokb = t0w + (mi >> 1) * 32;
                int tokp = tokb | (quad << 3) | ((mi & 1) << 2);
                half4 hv = { (half_t)acc[mi][ni][0], (half_t)acc[mi][ni][1],
                             (half_t)acc[mi][ni][2], (half_t)acc[mi][ni][3] };
                *(half4*)(v_ws + base + (size_t)d * 1024 + tokp) = hv;
            }
        }
    }
}

// ============================================================================
// Proj GEMM v3: REG-STAGED (v9 transformation applied). 128x192 tile, BK=32,
// 4 waves, grid 64x4 = 256 = EXACTLY 1/CU. 2 LDS buffers (40 KB), loads for
// t+1 issued at step top, ds_write after MFMA cluster, one barrier/step.
// Same chunk machinery as v9 (A chunks {2w,2w+1}, B chunks {3w..3w+2},
// row_log/q_log source swizzle, foff reads). Epilogue: r3's verified 4x6
// transpose-through-LDS (scratch carved from As/Bs), float4 stores.
// ============================================================================
__global__ __launch_bounds__(256, 2)
void gemm_proj(const half_t* __restrict__ A, const half_t* __restrict__ Bt,
               float* __restrict__ Cout, const float* __restrict__ bias)
{
    __shared__ half_t As[2][128 * 32];   // 2 x 8 KB
    __shared__ half_t Bs[2][192 * 32];   // 2 x 12 KB  => 40 KB

    const int lin  = blockIdx.x;                  // 0..255
    const int xcd  = lin & 7, rest = lin >> 3;    // rest 0..31
    const int m0 = ((rest >> 2) * 8 + xcd) * 128; // 64 m-strips
    const int n0 = (rest & 3) * 192;              // 4 n-strips

    const int tid  = threadIdx.x;
    const int lane = tid & 63;
    const int w    = tid >> 6;                    // 0..3
    const int wm   = w >> 1, wn = w & 1;
    const int quad = lane >> 4, l16 = lane & 15;

    const int b0p = (lane ^ (lane >> 2) ^ (lane >> 4)) & 1;
    const int b1p = ((lane >> 1) ^ (lane >> 3)) & 1;
    const int b2p = ((lane >> 2) ^ (lane >> 4)) & 1;
    const int row_log = ((lane >> 2) & 0xC) | ((lane >> 2) & 2) | b2p;
    const int q_log   = (b1p << 1) | b0p;
    const int foff = ((((l16 << 2) | quad) ^ (l16 & 7)) << 3);

    const half_t* aBase = A  + (size_t)(m0 + row_log) * 768 + q_log * 8;
    const half_t* bBase = Bt + (size_t)(n0 + row_log) * 768 + q_log * 8;

    floatx4 acc[4][6];
    #pragma unroll
    for (int i = 0; i < 4; i++)
        #pragma unroll
        for (int j = 0; j < 6; j++) acc[i][j] = (floatx4)0.0f;

    half8 sA0, sA1, sB0, sB1, sB2;

    #define PLOADR(KO)                                                         \
        do {                                                                   \
            sA0 = *(const half8*)(aBase + (size_t)((w*2+0)*16) * 768 + (KO));  \
            sA1 = *(const half8*)(aBase + (size_t)((w*2+1)*16) * 768 + (KO));  \
            sB0 = *(const half8*)(bBase + (size_t)((w*3+0)*16) * 768 + (KO));  \
            sB1 = *(const half8*)(bBase + (size_t)((w*3+1)*16) * 768 + (KO));  \
            sB2 = *(const half8*)(bBase + (size_t)((w*3+2)*16) * 768 + (KO));  \
        } while (0)

    #define PWRITES(BUF)                                                       \
        do {                                                                   \
            *(half8*)(&As[BUF][(w*2+0)*512 + lane*8]) = sA0;                   \
            *(half8*)(&As[BUF][(w*2+1)*512 + lane*8]) = sA1;                   \
            *(half8*)(&Bs[BUF][(w*3+0)*512 + lane*8]) = sB0;                   \
            *(half8*)(&Bs[BUF][(w*3+1)*512 + lane*8]) = sB1;                   \
            *(half8*)(&Bs[BUF][(w*3+2)*512 + lane*8]) = sB2;                   \
        } while (0)

    PLOADR(0);
    PWRITES(0);
    __syncthreads();

    #pragma unroll 1
    for (int t = 0; t < 24; ++t) {
        const int cur = t & 1;
        if (t < 23) PLOADR((t + 1) * 32);

        half8 a[4], b[6];
        #pragma unroll
        for (int mi = 0; mi < 4; mi++)
            a[mi] = *(const half8*)(&As[cur][(wm*4 + mi) * 512 + foff]);
        #pragma unroll
        for (int ni = 0; ni < 6; ni++)
            b[ni] = *(const half8*)(&Bs[cur][(wn*6 + ni) * 512 + foff]);
        #pragma unroll
        for (int mi = 0; mi < 4; mi++)
            #pragma unroll
            for (int ni = 0; ni < 6; ni++)
                acc[mi][ni] = MFMA_F16(a[mi], b[ni], acc[mi][ni]);

        if (t < 23) PWRITES(cur ^ 1);
        __syncthreads();
    }
    #undef PLOADR
    #undef PWRITES

    // epilogue (r3-verified): per-wave LDS transpose, rows padded to 100 f32
    float bias_v[6];
    #pragma unroll
    for (int ni = 0; ni < 6; ni++)
        bias_v[ni] = bias[n0 + wn * 96 + ni * 16 + l16];
    // scratch: 1600 f32 per wave, carved from As (waves 0,1) / Bs (waves 2,3)
    float* scratch = (w < 2 ? (float*)As : (float*)Bs) + (w & 1) * 1600;
    #pragma unroll
    for (int mi = 0; mi < 4; mi++) {
        #pragma unroll
        for (int ni = 0; ni < 6; ni++)
            #pragma unroll
            for (int r = 0; r < 4; r++)
                scratch[(quad * 4 + r) * 100 + ni * 16 + l16] =
                    acc[mi][ni][r] + bias_v[ni];
        #pragma unroll
        for (int i = 0; i < 6; i++) {
            int f = quad + i * 4;           // float4 index 0..23 (96 cols)
            float4 v4 = *(const float4*)(scratch + l16 * 100 + f * 4);
            int gm = m0 + wm * 64 + mi * 16 + l16;
            *(float4*)(Cout + (size_t)gm * 768 + n0 + wn * 96 + f * 4) = v4;
        }
    }
}

// ============================================================================
// Flash attention v6: v5 structure with K/V staging moved to REG-STAGING
// (v9 transformation): per wave 4 global b128 loads issued right after the
// top barrier (latency hides under S^T+softmax+PV of the current tile), 4
// ds_write_b128 after PV into buf^1. LDS layout bit-identical to the DMA
// deposit (dest row*64 + lane*8 == base + lane*16B); read side unchanged.
// Q prologue stays global_load_lds (once). LDS 48 KB -> 3 blocks/CU.
// ============================================================================
__global__ __launch_bounds__(256, 3)
void attn_kernel(const half_t* __restrict__ qT, const half_t* __restrict__ k,
                 const half_t* __restrict__ vT, half_t* __restrict__ a_ws)
{
    __shared__ __align__(16) half_t Kb[2][4096];
    __shared__ __align__(16) half_t Vb[2][4096];
    __shared__ __align__(16) half_t Qs[64 * 128];

    const int lin  = blockIdx.x;
    const int xcd  = lin & 7, rest = lin >> 3;
    const int qc   = rest & 7;                    // 0..7 (128-row q chunk)
    const int bh   = (rest >> 3) * 8 + xcd;       // 0..95; same bh -> same XCD

    const int tid  = threadIdx.x;
    const int lane = tid & 63;
    const int w    = tid >> 6;
    const int quad = lane >> 4, l16 = lane & 15;

    const half_t* qg = qT + (size_t)bh * 65536;   // [d][tok]
    const half_t* kg = k  + (size_t)bh * 65536;   // [key][d]
    const half_t* vg = vT + (size_t)bh * 65536;   // [d][tok'] permuted

    const int srow = lane >> 3;              // 0..7
    const int sch  = (lane & 7) ^ srow;      // swizzled chunk (source side)

    // stage Q^T tile [64 d][128 toks]
    #pragma unroll
    for (int j = 0; j < 4; j++) {
        int d0 = w * 16 + j * 4;
        async_copy16(qg + (size_t)(d0 + (lane >> 4)) * 1024 + qc * 128 + (lane & 15) * 8,
                     &Qs[d0 * 128]);
    }
    // prologue: K/V tile 0 via DMA (once)
    #pragma unroll
    for (int j = 0; j < 2; j++) {
        int row = j * 32 + w * 8;
        async_copy16(kg + (size_t)(row + srow) * 64 + sch * 8, &Kb[0][row * 64]);
        async_copy16(vg + (size_t)(row + srow) * 1024 + sch * 8, &Vb[0][row * 64]);
    }
    __syncthreads();   // drains Q stage + tile 0

    // Q fragments (B-operand of S^T MFMA): B[n=query l16][k=d quad*8+j]
    half8 qf[2][2];
    #pragma unroll
    for (int T = 0; T < 2; T++)
        #pragma unroll
        for (int ks = 0; ks < 2; ks++)
            #pragma unroll
            for (int j = 0; j < 8; j++)
                qf[T][ks][j] = Qs[(ks * 32 + quad * 8 + j) * 128
                                  + T * 64 + w * 16 + l16];

    floatx4 acc_o[2][4];
    floatx4 lacc[2];
    #pragma unroll
    for (int T = 0; T < 2; T++) {
        lacc[T] = (floatx4)0.0f;
        #pragma unroll
        for (int dt = 0; dt < 4; dt++) acc_o[T][dt] = (floatx4)0.0f;
    }

    const int xsw = l16 & 7;
    const half8 vone = { (half_t)1.0f, (half_t)1.0f, (half_t)1.0f, (half_t)1.0f,
                         (half_t)1.0f, (half_t)1.0f, (half_t)1.0f, (half_t)1.0f };

    half8 rk0, rk1, rv0, rv1;    // reg-staged K/V tile in flight

    for (int kt = 0; kt < 16; kt++) {
        const int cb = kt & 1;
        __syncthreads();               // publishes tile kt (written end of kt-1)
        if (kt < 15) {                 // issue loads for tile kt+1 EARLY
            rk0 = *(const half8*)(kg + (size_t)((kt + 1) * 64 + w * 8 + srow) * 64 + sch * 8);
            rk1 = *(const half8*)(kg + (size_t)((kt + 1) * 64 + 32 + w * 8 + srow) * 64 + sch * 8);
            rv0 = *(const half8*)(vg + (size_t)(w * 8 + srow) * 1024 + (kt + 1) * 64 + sch * 8);
            rv1 = *(const half8*)(vg + (size_t)(32 + w * 8 + srow) * 1024 + (kt + 1) * 64 + sch * 8);
        }
        const half_t* Kc = Kb[cb];
        const half_t* Vc = Vb[cb];

        // S^T = K . Q^T : A-frag = K[key=l16][d=quad*8+j] (LDS), B-frag = qf.
        floatx4 sc[2][4];
        #pragma unroll
        for (int T = 0; T < 2; T++)
            #pragma unroll
            for (int mt = 0; mt < 4; mt++) sc[T][mt] = (floatx4)0.0f;
        #pragma unroll
        for (int ks = 0; ks < 2; ks++)
            #pragma unroll
            for (int mt = 0; mt < 4; mt++) {
                half8 kf = *(const half8*)(Kc + (mt * 16 + l16) * 64
                                              + (((ks << 2) + quad) ^ xsw) * 8);
                sc[0][mt] = MFMA_F16(kf, qf[0][ks], sc[0][mt]);
                sc[1][mt] = MFMA_F16(kf, qf[1][ks], sc[1][mt]);
            }

        // P = exp(S), packed per 32-key group into 16x16x32 A-frags
        half8 pa[2][2];
        #pragma unroll
        for (int T = 0; T < 2; T++)
            #pragma unroll
            for (int g = 0; g < 2; g++) {
                half8 ph;
                #pragma unroll
                for (int r = 0; r < 4; r++) ph[r]     = (half_t)__expf(sc[T][2 * g][r]);
                #pragma unroll
                for (int r = 0; r < 4; r++) ph[4 + r] = (half_t)__expf(sc[T][2 * g + 1][r]);
                pa[T][g] = ph;
            }

        // l += P.1 and O += P.V'
        #pragma unroll
        for (int g = 0; g < 2; g++) {
            lacc[0] = MFMA_F16(pa[0][g], vone, lacc[0]);
            lacc[1] = MFMA_F16(pa[1][g], vone, lacc[1]);
            #pragma unroll
            for (int dt = 0; dt < 4; dt++) {
                half8 vb = *(const half8*)(Vc + (dt * 16 + l16) * 64
                                              + ((((g << 2) + quad) ^ xsw) << 3));
                acc_o[0][dt] = MFMA_F16(pa[0][g], vb, acc_o[0][dt]);
                acc_o[1][dt] = MFMA_F16(pa[1][g], vb, acc_o[1][dt]);
            }
        }

        if (kt < 15) {                 // deposit tile kt+1 into buf^1
            *(half8*)(&Kb[cb ^ 1][(w * 8) * 64 + lane * 8])      = rk0;
            *(half8*)(&Kb[cb ^ 1][(32 + w * 8) * 64 + lane * 8]) = rk1;
            *(half8*)(&Vb[cb ^ 1][(w * 8) * 64 + lane * 8])      = rv0;
            *(half8*)(&Vb[cb ^ 1][(32 + w * 8) * 64 + lane * 8]) = rv1;
        }
    }

    // epilogue: a_ws[(b*1024+n)*768 + h*64 + d]; O C-layout row=query quad*4+r
    const int b = bh / 12, h = bh - (bh / 12) * 12;
    #pragma unroll
    for (int T = 0; T < 2; T++)
        #pragma unroll
        for (int r = 0; r < 4; r++) {
            float inv = 1.0f / lacc[T][r];
            int n = qc * 128 + T * 64 + w * 16 + quad * 4 + r;
            half_t* op = a_ws + ((size_t)(b * 1024 + n)) * 768 + h * 64;
            #pragma unroll
            for (int dt = 0; dt < 4; dt++)
                op[dt * 16 + l16] = (half_t)(acc_o[T][dt][r] * inv);
        }
}

extern "C" void kernel_launch(void* const* d_in, const int* in_sizes, int n_in,
                              void* d_out, int out_size, void* d_ws, size_t ws_size,
                              hipStream_t stream)
{
    (void)in_sizes; (void)n_in; (void)out_size; (void)ws_size;
    const float* x      = (const float*)d_in[0];
    const float* w_qkv  = (const float*)d_in[1];
    const float* w_proj = (const float*)d_in[2];
    const float* b_proj = (const float*)d_in[3];
    float* out = (float*)d_out;

    // ws: qT | k | vT' | xh(->a_ws) | wqkvT | wprojT   (55.1 MB)
    half_t* ws     = (half_t*)d_ws;
    half_t* q_ws   = ws;                 // q transposed [bh][d][tok]
    half_t* k_ws   = ws + 6291456;
    half_t* v_ws   = ws + 2 * 6291456;   // permuted V^T (gemm epilogue)
    half_t* xh     = ws + 3 * 6291456;   // dead after gemm_qkv -> a_ws
    half_t* wqkvT  = ws + 4 * 6291456;
    half_t* wprojT = wqkvT + 1769472;
    half_t* a_ws   = xh;

    prep_kernel<<<dim3(6720), dim3(256), 0, stream>>>(x, w_qkv, w_proj, xh, wqkvT, wprojT);
    gemm_qkv<<<dim3(256), dim3(512), 0, stream>>>(xh, wqkvT, q_ws, k_ws, v_ws);
    attn_kernel<<<dim3(768), dim3(256), 0, stream>>>(q_ws, k_ws, v_ws, a_ws);
    gemm_proj<<<dim3(256), dim3(256), 0, stream>>>(a_ws, wprojT, out, b_proj);
}